// Round 16
// baseline (32.503 us; speedup 1.0000x reference)
//
#include <hip/hip_runtime.h>
#include <hip/hip_bf16.h>

#define B_ 8
#define N_ 64
#define T_ 512
#define D_ 128
#define H_ 7
#define TPB 4   // tiles (t-values) per block; grid = 4096/TPB = 1024 = 4 blocks/CU

typedef __attribute__((ext_vector_type(8))) short short8;   // 8 bf16 (MFMA A/B frag)
typedef __attribute__((ext_vector_type(4))) float f32x4;    // MFMA C/D frag
typedef __attribute__((ext_vector_type(4))) int   iv4;

union BF2 { __hip_bfloat162 h2; unsigned u; };
__device__ __forceinline__ unsigned pk2(float a, float b) {  // v_cvt_pk_bf16_f32 (RNE)
    BF2 r; r.h2 = __float22bfloat162_rn(make_float2(a, b)); return r.u;
}
__device__ __forceinline__ short8 cvt8(const float4& a, const float4& b) {
    iv4 v = { (int)pk2(a.x, a.y), (int)pk2(a.z, a.w),
              (int)pk2(b.x, b.y), (int)pk2(b.z, b.w) };
    return __builtin_bit_cast(short8, v);
}

// Raw barrier that does NOT drain vmcnt: in-flight global loads survive it.
__device__ __forceinline__ void lds_barrier() {
    asm volatile("s_waitcnt lgkmcnt(0)" ::: "memory");
    asm volatile("s_barrier" ::: "memory");
}

// R15 + prefetch depth 2: two register sets (g,h); tile i+2's 8 dwordx4 issue
// as soon as the current set's cvt retires -> ~4 KB in flight per CU (Little's
// law for ~450cy L3 latency at 21 GB/s/CU). LDS ping-pong, one lgkm-barrier
// per tile. Max-free softmax; per-h 1/Z post-PV.
// Frag layouts (m89-verified): A row=l&15,k=(l>>4)*8+j; B col=l&15,k same;
// C/D col=l&15, row=(l>>4)*4+reg.
__global__ __launch_bounds__(256, 4)
void MultiHeadPool_45226005627089_kernel(const float* __restrict__ others,
                                         const float* __restrict__ queries,
                                         float* __restrict__ out) {
    __shared__ __align__(16) ushort XL0[N_ * 136], XL1[N_ * 136]; // bf16 X, swizzled
    __shared__ __align__(16) ushort WL0[16 * 72],  WL1[16 * 72];  // bf16 e[h][n]
    __shared__ __align__(16) float  SM0[16 * 4],   SM1[16 * 4];   // (h,wave) partial sums

    const int tid = threadIdx.x;
    const int w   = tid >> 6;        // wave 0..3
    const int l   = tid & 63;
    const int c   = l & 15;
    const int p   = l >> 4;

    const int blk = blockIdx.x;          // 1024 blocks; tiles t0 .. t0+3
    const int b   = blk >> 7;            // 128 blocks per batch
    const int t0  = (blk & 127) * TPB;

    const int    n    = 16 * w + c;
    const int    swn  = ((n >> 3) & 3) << 4;        // d-chunk XOR swizzle for XL
    const float* xrow = others + ((size_t)b * N_ * T_ + t0) * D_
                               + (size_t)n * (T_ * D_) + 8 * p;
    float* obt = out + ((size_t)(b * T_ + t0)) * (H_ * D_);

    // ---- Q fragments (hoisted): col = h = c (clamped; masked at store); k = 32s+8p+j ----
    short8 qb0, qb1, qb2, qb3;
    {
        const float* qrow = queries + (c < H_ ? c : 0) * D_ + 8 * p;
        qb0 = cvt8(*(const float4*)(qrow +  0), *(const float4*)(qrow +  4));
        qb1 = cvt8(*(const float4*)(qrow + 32), *(const float4*)(qrow + 36));
        qb2 = cvt8(*(const float4*)(qrow + 64), *(const float4*)(qrow + 68));
        qb3 = cvt8(*(const float4*)(qrow + 96), *(const float4*)(qrow + 100));
    }

    const float scale = 0.0883883476483184f;  // 128^-0.5

    // prologue: issue tile-0 loads into set g, tile-1 loads into set h
    float4 g0 = *(const float4*)(xrow +  0), g1 = *(const float4*)(xrow +  4);
    float4 g2 = *(const float4*)(xrow + 32), g3 = *(const float4*)(xrow + 36);
    float4 g4 = *(const float4*)(xrow + 64), g5 = *(const float4*)(xrow + 68);
    float4 g6 = *(const float4*)(xrow + 96), g7 = *(const float4*)(xrow + 100);
    const float* hrow = xrow + D_;
    float4 h0 = *(const float4*)(hrow +  0), h1 = *(const float4*)(hrow +  4);
    float4 h2 = *(const float4*)(hrow + 32), h3 = *(const float4*)(hrow + 36);
    float4 h4 = *(const float4*)(hrow + 64), h5 = *(const float4*)(hrow + 68);
    float4 h6 = *(const float4*)(hrow + 96), h7 = *(const float4*)(hrow + 100);

#define TILE_BODY(IT, XL, WL, SM, P)                                           \
    do {                                                                       \
        /* cvt current set (waits on its own loads only) */                    \
        short8 xb0 = cvt8(P##0, P##1), xb1 = cvt8(P##2, P##3),                 \
               xb2 = cvt8(P##4, P##5), xb3 = cvt8(P##6, P##7);                 \
        /* refill this set with tile IT+2 (rides across 2 tiles of compute) */ \
        if ((IT) < TPB - 2) {                                                  \
            const float* yrow = xrow + ((IT) + 2) * D_;                        \
            P##0 = *(const float4*)(yrow +  0); P##1 = *(const float4*)(yrow +  4);\
            P##2 = *(const float4*)(yrow + 32); P##3 = *(const float4*)(yrow + 36);\
            P##4 = *(const float4*)(yrow + 64); P##5 = *(const float4*)(yrow + 68);\
            P##6 = *(const float4*)(yrow + 96); P##7 = *(const float4*)(yrow + 100);\
        }                                                                      \
        *(short8*)&XL[n * 136 + (( 0 + 8 * p) ^ swn)] = xb0;                   \
        *(short8*)&XL[n * 136 + ((32 + 8 * p) ^ swn)] = xb1;                   \
        *(short8*)&XL[n * 136 + ((64 + 8 * p) ^ swn)] = xb2;                   \
        *(short8*)&XL[n * 136 + ((96 + 8 * p) ^ swn)] = xb3;                   \
        {                                                                      \
            f32x4 c1 = {0.f, 0.f, 0.f, 0.f};                                   \
            c1 = __builtin_amdgcn_mfma_f32_16x16x32_bf16(xb0, qb0, c1, 0, 0, 0);\
            c1 = __builtin_amdgcn_mfma_f32_16x16x32_bf16(xb1, qb1, c1, 0, 0, 0);\
            c1 = __builtin_amdgcn_mfma_f32_16x16x32_bf16(xb2, qb2, c1, 0, 0, 0);\
            c1 = __builtin_amdgcn_mfma_f32_16x16x32_bf16(xb3, qb3, c1, 0, 0, 0);\
            float e0 = __expf(c1[0] * scale), e1 = __expf(c1[1] * scale);      \
            float e2 = __expf(c1[2] * scale), e3 = __expf(c1[3] * scale);      \
            float s_w = e0 + e1 + e2 + e3;                                     \
            s_w += __shfl_xor(s_w, 16);                                        \
            s_w += __shfl_xor(s_w, 32);                                        \
            if (l < 16) SM[c * 4 + w] = s_w;                                   \
            *(uint2*)&WL[c * 72 + 16 * w + 4 * p] =                            \
                make_uint2(pk2(e0, e1), pk2(e2, e3));                          \
        }                                                                      \
        lds_barrier();   /* buf[cur] ready; in-flight loads survive */         \
        {                                                                      \
            short8 a20 = *(const short8*)&WL[c * 72 +  0 + 8 * p];             \
            short8 a21 = *(const short8*)&WL[c * 72 + 32 + 8 * p];             \
            f32x4 o20, o21;                                                    \
            {                                                                  \
                const int dt = 2 * w;                                          \
                f32x4 acc = {0.f, 0.f, 0.f, 0.f};                              \
                const int b0 = (8 * p) * 136 + ((16 * dt + c) ^ (p << 4));     \
                short8 bf;                                                     \
                _Pragma("unroll")                                              \
                for (int jj = 0; jj < 8; ++jj) bf[jj] = (short)XL[b0 + 136 * jj];\
                acc = __builtin_amdgcn_mfma_f32_16x16x32_bf16(a20, bf, acc, 0, 0, 0);\
                const int b1 = (32 + 8 * p) * 136 + ((16 * dt + c) ^ (p << 4));\
                _Pragma("unroll")                                              \
                for (int jj = 0; jj < 8; ++jj) bf[jj] = (short)XL[b1 + 136 * jj];\
                acc = __builtin_amdgcn_mfma_f32_16x16x32_bf16(a21, bf, acc, 0, 0, 0);\
                o20 = acc;                                                     \
            }                                                                  \
            {                                                                  \
                const int dt = 2 * w + 1;                                      \
                f32x4 acc = {0.f, 0.f, 0.f, 0.f};                              \
                const int b0 = (8 * p) * 136 + ((16 * dt + c) ^ (p << 4));     \
                short8 bf;                                                     \
                _Pragma("unroll")                                              \
                for (int jj = 0; jj < 8; ++jj) bf[jj] = (short)XL[b0 + 136 * jj];\
                acc = __builtin_amdgcn_mfma_f32_16x16x32_bf16(a20, bf, acc, 0, 0, 0);\
                const int b1 = (32 + 8 * p) * 136 + ((16 * dt + c) ^ (p << 4));\
                _Pragma("unroll")                                              \
                for (int jj = 0; jj < 8; ++jj) bf[jj] = (short)XL[b1 + 136 * jj];\
                acc = __builtin_amdgcn_mfma_f32_16x16x32_bf16(a21, bf, acc, 0, 0, 0);\
                o21 = acc;                                                     \
            }                                                                  \
            float rz0, rz1, rz2, rz3;                                          \
            {                                                                  \
                const float4 z0 = *(const float4*)&SM[(4 * p + 0) * 4];        \
                const float4 z1 = *(const float4*)&SM[(4 * p + 1) * 4];        \
                const float4 z2 = *(const float4*)&SM[(4 * p + 2) * 4];        \
                const float4 z3 = *(const float4*)&SM[(4 * p + 3) * 4];        \
                rz0 = 1.0f / (z0.x + z0.y + z0.z + z0.w);                      \
                rz1 = 1.0f / (z1.x + z1.y + z1.z + z1.w);                      \
                rz2 = 1.0f / (z2.x + z2.y + z2.z + z2.w);                      \
                rz3 = 1.0f / (z3.x + z3.y + z3.z + z3.w);                      \
            }                                                                  \
            float* ob = obt + (IT) * (H_ * D_);                                \
            const int d0 = 16 * (2 * w) + c, d1 = d0 + 16;                     \
            if (4 * p + 0 < H_) { ob[(4*p+0) * D_ + d0] = o20[0] * rz0;        \
                                  ob[(4*p+0) * D_ + d1] = o21[0] * rz0; }      \
            if (4 * p + 1 < H_) { ob[(4*p+1) * D_ + d0] = o20[1] * rz1;        \
                                  ob[(4*p+1) * D_ + d1] = o21[1] * rz1; }      \
            if (4 * p + 2 < H_) { ob[(4*p+2) * D_ + d0] = o20[2] * rz2;        \
                                  ob[(4*p+2) * D_ + d1] = o21[2] * rz2; }      \
            if (4 * p + 3 < H_) { ob[(4*p+3) * D_ + d0] = o20[3] * rz3;        \
                                  ob[(4*p+3) * D_ + d1] = o21[3] * rz3; }      \
        }                                                                      \
        /* no second barrier: next tile stages into the OTHER buffer */        \
    } while (0)

    TILE_BODY(0, XL0, WL0, SM0, g);
    TILE_BODY(1, XL1, WL1, SM1, h);
    TILE_BODY(2, XL0, WL0, SM0, g);
    TILE_BODY(3, XL1, WL1, SM1, h);
#undef TILE_BODY
}

extern "C" void kernel_launch(void* const* d_in, const int* in_sizes, int n_in,
                              void* d_out, int out_size, void* d_ws, size_t ws_size,
                              hipStream_t stream) {
    // d_in[0] = ego (B,T,D) -- unused by the reference computation
    const float* others  = (const float*)d_in[1];   // (B,N,T,D) f32
    const float* queries = (const float*)d_in[2];   // (H,D) f32
    float* out = (float*)d_out;                     // (B,T,H,D) f32

    dim3 grid(B_ * T_ / TPB);
    dim3 block(256);
    MultiHeadPool_45226005627089_kernel<<<grid, block, 0, stream>>>(others, queries, out);
}

// Round 17
// 28.748 us; speedup vs baseline: 1.1306x; 1.1306x over previous
//
#include <hip/hip_runtime.h>
#include <hip/hip_bf16.h>

#define B_ 8
#define N_ 64
#define T_ 512
#define D_ 128
#define H_ 7
#define TPB 4   // tiles (t-values) per block; grid = 4096/TPB = 1024 = 4 blocks/CU

typedef __attribute__((ext_vector_type(8))) short short8;   // 8 bf16 (MFMA A/B frag)
typedef __attribute__((ext_vector_type(4))) float f32x4;    // MFMA C/D frag
typedef __attribute__((ext_vector_type(4))) int   iv4;

union BF2 { __hip_bfloat162 h2; unsigned u; };
__device__ __forceinline__ unsigned pk2(float a, float b) {  // v_cvt_pk_bf16_f32 (RNE)
    BF2 r; r.h2 = __float22bfloat162_rn(make_float2(a, b)); return r.u;
}
__device__ __forceinline__ short8 cvt8(const float4& a, const float4& b) {
    iv4 v = { (int)pk2(a.x, a.y), (int)pk2(a.z, a.w),
              (int)pk2(b.x, b.y), (int)pk2(b.z, b.w) };
    return __builtin_bit_cast(short8, v);
}

// Raw barrier that does NOT drain vmcnt: in-flight global loads survive it.
__device__ __forceinline__ void lds_barrier() {
    asm volatile("s_waitcnt lgkmcnt(0)" ::: "memory");
    asm volatile("s_barrier" ::: "memory");
}

// R15 (best: 28.2 us — depth-1 rolling prefetch, ping-pong LDS, one
// lgkm-barrier per tile) + s_setprio(1) around the MFMA clusters (T5):
// lgkm-only barriers allow wave skew, so the CU scheduler has role
// diversity to arbitrate; favor MFMA-entering waves.
// Max-free softmax (logits ~ N(0,1)); per-h 1/Z post-PV.
// Frag layouts (m89-verified): A row=l&15,k=(l>>4)*8+j; B col=l&15,k same;
// C/D col=l&15, row=(l>>4)*4+reg.
__global__ __launch_bounds__(256, 4)
void MultiHeadPool_45226005627089_kernel(const float* __restrict__ others,
                                         const float* __restrict__ queries,
                                         float* __restrict__ out) {
    __shared__ __align__(16) ushort XL0[N_ * 136], XL1[N_ * 136]; // bf16 X, swizzled
    __shared__ __align__(16) ushort WL0[16 * 72],  WL1[16 * 72];  // bf16 e[h][n]
    __shared__ __align__(16) float  SM0[16 * 4],   SM1[16 * 4];   // (h,wave) partial sums

    const int tid = threadIdx.x;
    const int w   = tid >> 6;        // wave 0..3
    const int l   = tid & 63;
    const int c   = l & 15;
    const int p   = l >> 4;

    const int blk = blockIdx.x;          // 1024 blocks; tiles t0 .. t0+3
    const int b   = blk >> 7;            // 128 blocks per batch
    const int t0  = (blk & 127) * TPB;

    const int    n    = 16 * w + c;
    const int    swn  = ((n >> 3) & 3) << 4;        // d-chunk XOR swizzle for XL
    const float* xrow = others + ((size_t)b * N_ * T_ + t0) * D_
                               + (size_t)n * (T_ * D_) + 8 * p;
    float* obt = out + ((size_t)(b * T_ + t0)) * (H_ * D_);

    // ---- Q fragments (hoisted): col = h = c (clamped; masked at store); k = 32s+8p+j ----
    short8 qb0, qb1, qb2, qb3;
    {
        const float* qrow = queries + (c < H_ ? c : 0) * D_ + 8 * p;
        qb0 = cvt8(*(const float4*)(qrow +  0), *(const float4*)(qrow +  4));
        qb1 = cvt8(*(const float4*)(qrow + 32), *(const float4*)(qrow + 36));
        qb2 = cvt8(*(const float4*)(qrow + 64), *(const float4*)(qrow + 68));
        qb3 = cvt8(*(const float4*)(qrow + 96), *(const float4*)(qrow + 100));
    }

    const float scale = 0.0883883476483184f;  // 128^-0.5

    // prologue: issue tile-0 loads
    float4 g0 = *(const float4*)(xrow +  0), g1 = *(const float4*)(xrow +  4);
    float4 g2 = *(const float4*)(xrow + 32), g3 = *(const float4*)(xrow + 36);
    float4 g4 = *(const float4*)(xrow + 64), g5 = *(const float4*)(xrow + 68);
    float4 g6 = *(const float4*)(xrow + 96), g7 = *(const float4*)(xrow + 100);

#define TILE_BODY(IT, XL, WL, SM)                                              \
    do {                                                                       \
        short8 xb0 = cvt8(g0, g1), xb1 = cvt8(g2, g3),                         \
               xb2 = cvt8(g4, g5), xb3 = cvt8(g6, g7);                         \
        if ((IT) < TPB - 1) {                                                  \
            const float* yrow = xrow + ((IT) + 1) * D_;                        \
            g0 = *(const float4*)(yrow +  0); g1 = *(const float4*)(yrow +  4);\
            g2 = *(const float4*)(yrow + 32); g3 = *(const float4*)(yrow + 36);\
            g4 = *(const float4*)(yrow + 64); g5 = *(const float4*)(yrow + 68);\
            g6 = *(const float4*)(yrow + 96); g7 = *(const float4*)(yrow + 100);\
        }                                                                      \
        *(short8*)&XL[n * 136 + (( 0 + 8 * p) ^ swn)] = xb0;                   \
        *(short8*)&XL[n * 136 + ((32 + 8 * p) ^ swn)] = xb1;                   \
        *(short8*)&XL[n * 136 + ((64 + 8 * p) ^ swn)] = xb2;                   \
        *(short8*)&XL[n * 136 + ((96 + 8 * p) ^ swn)] = xb3;                   \
        {                                                                      \
            __builtin_amdgcn_s_setprio(1);                                     \
            f32x4 c1 = {0.f, 0.f, 0.f, 0.f};                                   \
            c1 = __builtin_amdgcn_mfma_f32_16x16x32_bf16(xb0, qb0, c1, 0, 0, 0);\
            c1 = __builtin_amdgcn_mfma_f32_16x16x32_bf16(xb1, qb1, c1, 0, 0, 0);\
            c1 = __builtin_amdgcn_mfma_f32_16x16x32_bf16(xb2, qb2, c1, 0, 0, 0);\
            c1 = __builtin_amdgcn_mfma_f32_16x16x32_bf16(xb3, qb3, c1, 0, 0, 0);\
            __builtin_amdgcn_s_setprio(0);                                     \
            float e0 = __expf(c1[0] * scale), e1 = __expf(c1[1] * scale);      \
            float e2 = __expf(c1[2] * scale), e3 = __expf(c1[3] * scale);      \
            float s_w = e0 + e1 + e2 + e3;                                     \
            s_w += __shfl_xor(s_w, 16);                                        \
            s_w += __shfl_xor(s_w, 32);                                        \
            if (l < 16) SM[c * 4 + w] = s_w;                                   \
            *(uint2*)&WL[c * 72 + 16 * w + 4 * p] =                            \
                make_uint2(pk2(e0, e1), pk2(e2, e3));                          \
        }                                                                      \
        lds_barrier();   /* buf[cur] ready; in-flight loads survive */         \
        {                                                                      \
            short8 a20 = *(const short8*)&WL[c * 72 +  0 + 8 * p];             \
            short8 a21 = *(const short8*)&WL[c * 72 + 32 + 8 * p];             \
            f32x4 o20, o21;                                                    \
            __builtin_amdgcn_s_setprio(1);                                     \
            {                                                                  \
                const int dt = 2 * w;                                          \
                f32x4 acc = {0.f, 0.f, 0.f, 0.f};                              \
                const int b0 = (8 * p) * 136 + ((16 * dt + c) ^ (p << 4));     \
                short8 bf;                                                     \
                _Pragma("unroll")                                              \
                for (int jj = 0; jj < 8; ++jj) bf[jj] = (short)XL[b0 + 136 * jj];\
                acc = __builtin_amdgcn_mfma_f32_16x16x32_bf16(a20, bf, acc, 0, 0, 0);\
                const int b1 = (32 + 8 * p) * 136 + ((16 * dt + c) ^ (p << 4));\
                _Pragma("unroll")                                              \
                for (int jj = 0; jj < 8; ++jj) bf[jj] = (short)XL[b1 + 136 * jj];\
                acc = __builtin_amdgcn_mfma_f32_16x16x32_bf16(a21, bf, acc, 0, 0, 0);\
                o20 = acc;                                                     \
            }                                                                  \
            {                                                                  \
                const int dt = 2 * w + 1;                                      \
                f32x4 acc = {0.f, 0.f, 0.f, 0.f};                              \
                const int b0 = (8 * p) * 136 + ((16 * dt + c) ^ (p << 4));     \
                short8 bf;                                                     \
                _Pragma("unroll")                                              \
                for (int jj = 0; jj < 8; ++jj) bf[jj] = (short)XL[b0 + 136 * jj];\
                acc = __builtin_amdgcn_mfma_f32_16x16x32_bf16(a20, bf, acc, 0, 0, 0);\
                const int b1 = (32 + 8 * p) * 136 + ((16 * dt + c) ^ (p << 4));\
                _Pragma("unroll")                                              \
                for (int jj = 0; jj < 8; ++jj) bf[jj] = (short)XL[b1 + 136 * jj];\
                acc = __builtin_amdgcn_mfma_f32_16x16x32_bf16(a21, bf, acc, 0, 0, 0);\
                o21 = acc;                                                     \
            }                                                                  \
            __builtin_amdgcn_s_setprio(0);                                     \
            float rz0, rz1, rz2, rz3;                                          \
            {                                                                  \
                const float4 z0 = *(const float4*)&SM[(4 * p + 0) * 4];        \
                const float4 z1 = *(const float4*)&SM[(4 * p + 1) * 4];        \
                const float4 z2 = *(const float4*)&SM[(4 * p + 2) * 4];        \
                const float4 z3 = *(const float4*)&SM[(4 * p + 3) * 4];        \
                rz0 = 1.0f / (z0.x + z0.y + z0.z + z0.w);                      \
                rz1 = 1.0f / (z1.x + z1.y + z1.z + z1.w);                      \
                rz2 = 1.0f / (z2.x + z2.y + z2.z + z2.w);                      \
                rz3 = 1.0f / (z3.x + z3.y + z3.z + z3.w);                      \
            }                                                                  \
            float* ob = obt + (IT) * (H_ * D_);                                \
            const int d0 = 16 * (2 * w) + c, d1 = d0 + 16;                     \
            if (4 * p + 0 < H_) { ob[(4*p+0) * D_ + d0] = o20[0] * rz0;        \
                                  ob[(4*p+0) * D_ + d1] = o21[0] * rz0; }      \
            if (4 * p + 1 < H_) { ob[(4*p+1) * D_ + d0] = o20[1] * rz1;        \
                                  ob[(4*p+1) * D_ + d1] = o21[1] * rz1; }      \
            if (4 * p + 2 < H_) { ob[(4*p+2) * D_ + d0] = o20[2] * rz2;        \
                                  ob[(4*p+2) * D_ + d1] = o21[2] * rz2; }      \
            if (4 * p + 3 < H_) { ob[(4*p+3) * D_ + d0] = o20[3] * rz3;        \
                                  ob[(4*p+3) * D_ + d1] = o21[3] * rz3; }      \
        }                                                                      \
        /* no second barrier: next tile stages into the OTHER buffer */        \
    } while (0)

    TILE_BODY(0, XL0, WL0, SM0);
    TILE_BODY(1, XL1, WL1, SM1);
    TILE_BODY(2, XL0, WL0, SM0);
    TILE_BODY(3, XL1, WL1, SM1);
#undef TILE_BODY
}

extern "C" void kernel_launch(void* const* d_in, const int* in_sizes, int n_in,
                              void* d_out, int out_size, void* d_ws, size_t ws_size,
                              hipStream_t stream) {
    // d_in[0] = ego (B,T,D) -- unused by the reference computation
    const float* others  = (const float*)d_in[1];   // (B,N,T,D) f32
    const float* queries = (const float*)d_in[2];   // (H,D) f32
    float* out = (float*)d_out;                     // (B,T,H,D) f32

    dim3 grid(B_ * T_ / TPB);
    dim3 block(256);
    MultiHeadPool_45226005627089_kernel<<<grid, block, 0, stream>>>(others, queries, out);
}

// Round 18
// 28.338 us; speedup vs baseline: 1.1470x; 1.0145x over previous
//
#include <hip/hip_runtime.h>
#include <hip/hip_bf16.h>

#define B_ 8
#define N_ 64
#define T_ 512
#define D_ 128
#define H_ 7
#define TPB 4   // tiles (t-values) per block; grid = 4096/TPB = 1024 = 4 blocks/CU

typedef __attribute__((ext_vector_type(8))) short short8;   // 8 bf16 (MFMA A/B frag)
typedef __attribute__((ext_vector_type(4))) float f32x4;    // MFMA C/D frag
typedef __attribute__((ext_vector_type(4))) int   iv4;

union BF2 { __hip_bfloat162 h2; unsigned u; };
__device__ __forceinline__ unsigned pk2(float a, float b) {  // v_cvt_pk_bf16_f32 (RNE)
    BF2 r; r.h2 = __float22bfloat162_rn(make_float2(a, b)); return r.u;
}
__device__ __forceinline__ short8 cvt8(const float4& a, const float4& b) {
    iv4 v = { (int)pk2(a.x, a.y), (int)pk2(a.z, a.w),
              (int)pk2(b.x, b.y), (int)pk2(b.z, b.w) };
    return __builtin_bit_cast(short8, v);
}

// Raw barrier that does NOT drain vmcnt: in-flight global loads survive it.
__device__ __forceinline__ void lds_barrier() {
    asm volatile("s_waitcnt lgkmcnt(0)" ::: "memory");
    asm volatile("s_barrier" ::: "memory");
}

// FINAL (R15 structure, measured best 28.2 us = 84% of copy-ceiling BW):
// - one block per 4 consecutive t (grid 1024 = 4 blocks/CU, single generation)
// - depth-1 rolling register prefetch: tile i+1's 8 dwordx4 issue before tile
//   i's compute; lgkm-only barriers keep them in flight (s_waitcnt vmcnt NOT
//   drained -- the single biggest lever, -14%)
// - ping-pong LDS (XL/WL/SM x2), ONE barrier per tile
// - MFMA datapath: QK^T and PV via mfma_f32_16x16x32_bf16; X staged to LDS
//   bf16-swizzled; PV B-operand gathered via 16b reads (conflict-free XOR map)
// - max-free softmax (logits ~ N(0,1), exp bounded); per-h 1/Z applied post-PV
// Frag layouts (m89-verified): A row=l&15,k=(l>>4)*8+j; B col=l&15,k same;
// C/D col=l&15, row=(l>>4)*4+reg.
__global__ __launch_bounds__(256, 4)
void MultiHeadPool_45226005627089_kernel(const float* __restrict__ others,
                                         const float* __restrict__ queries,
                                         float* __restrict__ out) {
    __shared__ __align__(16) ushort XL0[N_ * 136], XL1[N_ * 136]; // bf16 X, swizzled
    __shared__ __align__(16) ushort WL0[16 * 72],  WL1[16 * 72];  // bf16 e[h][n]
    __shared__ __align__(16) float  SM0[16 * 4],   SM1[16 * 4];   // (h,wave) partial sums

    const int tid = threadIdx.x;
    const int w   = tid >> 6;        // wave 0..3
    const int l   = tid & 63;
    const int c   = l & 15;
    const int p   = l >> 4;

    const int blk = blockIdx.x;          // 1024 blocks; tiles t0 .. t0+3
    const int b   = blk >> 7;            // 128 blocks per batch
    const int t0  = (blk & 127) * TPB;

    const int    n    = 16 * w + c;
    const int    swn  = ((n >> 3) & 3) << 4;        // d-chunk XOR swizzle for XL
    const float* xrow = others + ((size_t)b * N_ * T_ + t0) * D_
                               + (size_t)n * (T_ * D_) + 8 * p;
    float* obt = out + ((size_t)(b * T_ + t0)) * (H_ * D_);

    // ---- Q fragments (hoisted): col = h = c (clamped; masked at store); k = 32s+8p+j ----
    short8 qb0, qb1, qb2, qb3;
    {
        const float* qrow = queries + (c < H_ ? c : 0) * D_ + 8 * p;
        qb0 = cvt8(*(const float4*)(qrow +  0), *(const float4*)(qrow +  4));
        qb1 = cvt8(*(const float4*)(qrow + 32), *(const float4*)(qrow + 36));
        qb2 = cvt8(*(const float4*)(qrow + 64), *(const float4*)(qrow + 68));
        qb3 = cvt8(*(const float4*)(qrow + 96), *(const float4*)(qrow + 100));
    }

    const float scale = 0.0883883476483184f;  // 128^-0.5

    // prologue: issue tile-0 loads
    float4 g0 = *(const float4*)(xrow +  0), g1 = *(const float4*)(xrow +  4);
    float4 g2 = *(const float4*)(xrow + 32), g3 = *(const float4*)(xrow + 36);
    float4 g4 = *(const float4*)(xrow + 64), g5 = *(const float4*)(xrow + 68);
    float4 g6 = *(const float4*)(xrow + 96), g7 = *(const float4*)(xrow + 100);

#define TILE_BODY(IT, XL, WL, SM)                                              \
    do {                                                                       \
        short8 xb0 = cvt8(g0, g1), xb1 = cvt8(g2, g3),                         \
               xb2 = cvt8(g4, g5), xb3 = cvt8(g6, g7);                         \
        if ((IT) < TPB - 1) {                                                  \
            const float* yrow = xrow + ((IT) + 1) * D_;                        \
            g0 = *(const float4*)(yrow +  0); g1 = *(const float4*)(yrow +  4);\
            g2 = *(const float4*)(yrow + 32); g3 = *(const float4*)(yrow + 36);\
            g4 = *(const float4*)(yrow + 64); g5 = *(const float4*)(yrow + 68);\
            g6 = *(const float4*)(yrow + 96); g7 = *(const float4*)(yrow + 100);\
        }                                                                      \
        *(short8*)&XL[n * 136 + (( 0 + 8 * p) ^ swn)] = xb0;                   \
        *(short8*)&XL[n * 136 + ((32 + 8 * p) ^ swn)] = xb1;                   \
        *(short8*)&XL[n * 136 + ((64 + 8 * p) ^ swn)] = xb2;                   \
        *(short8*)&XL[n * 136 + ((96 + 8 * p) ^ swn)] = xb3;                   \
        {                                                                      \
            f32x4 c1 = {0.f, 0.f, 0.f, 0.f};                                   \
            c1 = __builtin_amdgcn_mfma_f32_16x16x32_bf16(xb0, qb0, c1, 0, 0, 0);\
            c1 = __builtin_amdgcn_mfma_f32_16x16x32_bf16(xb1, qb1, c1, 0, 0, 0);\
            c1 = __builtin_amdgcn_mfma_f32_16x16x32_bf16(xb2, qb2, c1, 0, 0, 0);\
            c1 = __builtin_amdgcn_mfma_f32_16x16x32_bf16(xb3, qb3, c1, 0, 0, 0);\
            float e0 = __expf(c1[0] * scale), e1 = __expf(c1[1] * scale);      \
            float e2 = __expf(c1[2] * scale), e3 = __expf(c1[3] * scale);      \
            float s_w = e0 + e1 + e2 + e3;                                     \
            s_w += __shfl_xor(s_w, 16);                                        \
            s_w += __shfl_xor(s_w, 32);                                        \
            if (l < 16) SM[c * 4 + w] = s_w;                                   \
            *(uint2*)&WL[c * 72 + 16 * w + 4 * p] =                            \
                make_uint2(pk2(e0, e1), pk2(e2, e3));                          \
        }                                                                      \
        lds_barrier();   /* buf[cur] ready; in-flight loads survive */         \
        {                                                                      \
            short8 a20 = *(const short8*)&WL[c * 72 +  0 + 8 * p];             \
            short8 a21 = *(const short8*)&WL[c * 72 + 32 + 8 * p];             \
            f32x4 o20, o21;                                                    \
            {                                                                  \
                const int dt = 2 * w;                                          \
                f32x4 acc = {0.f, 0.f, 0.f, 0.f};                              \
                const int b0 = (8 * p) * 136 + ((16 * dt + c) ^ (p << 4));     \
                short8 bf;                                                     \
                _Pragma("unroll")                                              \
                for (int jj = 0; jj < 8; ++jj) bf[jj] = (short)XL[b0 + 136 * jj];\
                acc = __builtin_amdgcn_mfma_f32_16x16x32_bf16(a20, bf, acc, 0, 0, 0);\
                const int b1 = (32 + 8 * p) * 136 + ((16 * dt + c) ^ (p << 4));\
                _Pragma("unroll")                                              \
                for (int jj = 0; jj < 8; ++jj) bf[jj] = (short)XL[b1 + 136 * jj];\
                acc = __builtin_amdgcn_mfma_f32_16x16x32_bf16(a21, bf, acc, 0, 0, 0);\
                o20 = acc;                                                     \
            }                                                                  \
            {                                                                  \
                const int dt = 2 * w + 1;                                      \
                f32x4 acc = {0.f, 0.f, 0.f, 0.f};                              \
                const int b0 = (8 * p) * 136 + ((16 * dt + c) ^ (p << 4));     \
                short8 bf;                                                     \
                _Pragma("unroll")                                              \
                for (int jj = 0; jj < 8; ++jj) bf[jj] = (short)XL[b0 + 136 * jj];\
                acc = __builtin_amdgcn_mfma_f32_16x16x32_bf16(a20, bf, acc, 0, 0, 0);\
                const int b1 = (32 + 8 * p) * 136 + ((16 * dt + c) ^ (p << 4));\
                _Pragma("unroll")                                              \
                for (int jj = 0; jj < 8; ++jj) bf[jj] = (short)XL[b1 + 136 * jj];\
                acc = __builtin_amdgcn_mfma_f32_16x16x32_bf16(a21, bf, acc, 0, 0, 0);\
                o21 = acc;                                                     \
            }                                                                  \
            float rz0, rz1, rz2, rz3;                                          \
            {                                                                  \
                const float4 z0 = *(const float4*)&SM[(4 * p + 0) * 4];        \
                const float4 z1 = *(const float4*)&SM[(4 * p + 1) * 4];        \
                const float4 z2 = *(const float4*)&SM[(4 * p + 2) * 4];        \
                const float4 z3 = *(const float4*)&SM[(4 * p + 3) * 4];        \
                rz0 = 1.0f / (z0.x + z0.y + z0.z + z0.w);                      \
                rz1 = 1.0f / (z1.x + z1.y + z1.z + z1.w);                      \
                rz2 = 1.0f / (z2.x + z2.y + z2.z + z2.w);                      \
                rz3 = 1.0f / (z3.x + z3.y + z3.z + z3.w);                      \
            }                                                                  \
            float* ob = obt + (IT) * (H_ * D_);                                \
            const int d0 = 16 * (2 * w) + c, d1 = d0 + 16;                     \
            if (4 * p + 0 < H_) { ob[(4*p+0) * D_ + d0] = o20[0] * rz0;        \
                                  ob[(4*p+0) * D_ + d1] = o21[0] * rz0; }      \
            if (4 * p + 1 < H_) { ob[(4*p+1) * D_ + d0] = o20[1] * rz1;        \
                                  ob[(4*p+1) * D_ + d1] = o21[1] * rz1; }      \
            if (4 * p + 2 < H_) { ob[(4*p+2) * D_ + d0] = o20[2] * rz2;        \
                                  ob[(4*p+2) * D_ + d1] = o21[2] * rz2; }      \
            if (4 * p + 3 < H_) { ob[(4*p+3) * D_ + d0] = o20[3] * rz3;        \
                                  ob[(4*p+3) * D_ + d1] = o21[3] * rz3; }      \
        }                                                                      \
        /* no second barrier: next tile stages into the OTHER buffer */        \
    } while (0)

    TILE_BODY(0, XL0, WL0, SM0);
    TILE_BODY(1, XL1, WL1, SM1);
    TILE_BODY(2, XL0, WL0, SM0);
    TILE_BODY(3, XL1, WL1, SM1);
#undef TILE_BODY
}

extern "C" void kernel_launch(void* const* d_in, const int* in_sizes, int n_in,
                              void* d_out, int out_size, void* d_ws, size_t ws_size,
                              hipStream_t stream) {
    // d_in[0] = ego (B,T,D) -- unused by the reference computation
    const float* others  = (const float*)d_in[1];   // (B,N,T,D) f32
    const float* queries = (const float*)d_in[2];   // (H,D) f32
    float* out = (float*)d_out;                     // (B,T,H,D) f32

    dim3 grid(B_ * T_ / TPB);
    dim3 block(256);
    MultiHeadPool_45226005627089_kernel<<<grid, block, 0, stream>>>(others, queries, out);
}